// Round 5
// baseline (565.038 us; speedup 1.0000x reference)
//
#include <hip/hip_runtime.h>

// GraphSAGE 2-layer forward, MI355X. Round 4:
//  - feature-segmented gathers (64-feat windows -> 2.56 MB table slices, L2-resident)
//  - fused layer-2 GEMM: [t2 | self] = h1 @ [Wn2^T | Ws2^T], mixed f16/f32 epilogue
// Layer1: A1b[20000][640] f16 = [x | mean_agg(x) | 0]; h1 = relu(A1b @ Wt1^T + b1) (f16)
// Layer2: t2 = h1@Wn2 (f16), self = h1@Ws2 + b2 (f32); out = mean_agg(t2) + self

typedef _Float16 f16;
typedef _Float16 f16x4 __attribute__((ext_vector_type(4)));
typedef _Float16 f16x8 __attribute__((ext_vector_type(8)));
typedef float f32x4 __attribute__((ext_vector_type(4)));

constexpr int NN = 20000;   // nodes
constexpr int NE = 640000;  // edges
constexpr int F0 = 300;     // in feats
constexpr int F1 = 512;     // hidden
constexpr int F2 = 256;     // classes
constexpr int KP1 = 640;    // padded concat-K for layer 1 (multiple of 64)

// ---------------- input conversion ----------------
__global__ void conv_x_kernel(const float* __restrict__ x, f16* __restrict__ A1b) {
    long idx = (long)blockIdx.x * 256 + threadIdx.x;  // m*80 + c
    if (idx >= (long)NN * 80) return;
    int m = (int)(idx / 80), c = (int)(idx % 80);
    if (c < 75) {
        float4 v = *(const float4*)(x + (long)m * F0 + 4 * c);
        f16x4 h = {(f16)v.x, (f16)v.y, (f16)v.z, (f16)v.w};
        *(f16x4*)(A1b + (long)m * KP1 + 4 * c) = h;
    } else {
        f16x8 z = {};
        *(f16x8*)(A1b + (long)m * KP1 + 600 + (c - 75) * 8) = z;
    }
}

// Wt1[n][k] (f16, [512][640]) = k<300 ? Ws1[k][n] : k<600 ? Wn1[k-300][n] : 0
__global__ void prep_w1_kernel(const float* __restrict__ Ws1, const float* __restrict__ Wn1,
                               f16* __restrict__ Wt1) {
    int idx = blockIdx.x * 256 + threadIdx.x;
    if (idx >= F1 * KP1) return;
    int n = idx / KP1, k = idx % KP1;
    float v = 0.f;
    if (k < 300) v = Ws1[k * F1 + n];
    else if (k < 600) v = Wn1[(k - 300) * F1 + n];
    Wt1[idx] = (f16)v;
}

// Wt2cat[n][k] ([512][512]) : n<256 -> Wn2[k][n] ; n>=256 -> Ws2[k][n-256]
__global__ void prep_w2cat_kernel(const float* __restrict__ Ws2, const float* __restrict__ Wn2,
                                  f16* __restrict__ Wt) {
    int idx = blockIdx.x * 256 + threadIdx.x;
    if (idx >= 2 * F2 * F1) return;
    int n = idx / F1, k = idx % F1;
    float v = (n < F2) ? Wn2[k * F2 + n] : Ws2[k * F2 + (n - F2)];
    Wt[idx] = (f16)v;
}

// ---------------- CSR build ----------------
__global__ void count_kernel(const int* __restrict__ dst, int* __restrict__ cnt) {
    int e = blockIdx.x * 256 + threadIdx.x;
    if (e < NE) atomicAdd(&cnt[dst[e]], 1);
}

__global__ __launch_bounds__(1024) void scan_kernel(const int* __restrict__ cnt,
                                                    int* __restrict__ row_ptr,
                                                    int* __restrict__ cursor) {
    constexpr int CH = (NN + 1023) / 1024;  // 20
    __shared__ int part[1024];
    const int t = threadIdx.x;
    int base = t * CH;
    int s = 0;
    #pragma unroll
    for (int i = 0; i < CH; ++i) {
        int idx = base + i;
        if (idx < NN) s += cnt[idx];
    }
    part[t] = s;
    __syncthreads();
    #pragma unroll
    for (int off = 1; off < 1024; off <<= 1) {
        int v = (t >= off) ? part[t - off] : 0;
        __syncthreads();
        part[t] += v;
        __syncthreads();
    }
    int run = (t == 0) ? 0 : part[t - 1];
    #pragma unroll
    for (int i = 0; i < CH; ++i) {
        int idx = base + i;
        if (idx < NN) {
            row_ptr[idx] = run;
            cursor[idx] = run;
            run += cnt[idx];
        }
    }
    if (t == 1023) row_ptr[NN] = part[1023];
}

__global__ void fill_kernel(const int* __restrict__ src, const int* __restrict__ dst,
                            int* __restrict__ cursor, int* __restrict__ csr_src) {
    int e = blockIdx.x * 256 + threadIdx.x;
    if (e >= NE) return;
    int pos = atomicAdd(&cursor[dst[e]], 1);
    csr_src[pos] = src[e];
}

// ---------------- segmented gathers ----------------
// gather1 segment: VW f16 feats per thread, NCH threads per node; feats [c0, c0+VW*NCH)
// reads A1b cols c0.. (within x region), writes mean into A1b cols 300+c0..
template<int VW, int NCH>
__global__ __launch_bounds__(256) void gather1_kernel(const int* __restrict__ row_ptr,
                                                      const int* __restrict__ csr,
                                                      f16* __restrict__ A1b, int c0) {
    long idx = (long)blockIdx.x * 256 + threadIdx.x;
    if (idx >= (long)NN * NCH) return;
    int m = (int)(idx / NCH);
    int off = c0 + (int)(idx % NCH) * VW;
    int beg = row_ptr[m], end = row_ptr[m + 1];
    float a[VW] = {};
    for (int e = beg; e < end; ++e) {
        int s = csr[e];
        if (VW == 8) {
            f16x8 v = *(const f16x8*)(A1b + (long)s * KP1 + off);
            #pragma unroll
            for (int j = 0; j < 8; ++j) a[j] += (float)v[j];
        } else {
            f16x4 v = *(const f16x4*)(A1b + (long)s * KP1 + off);
            #pragma unroll
            for (int j = 0; j < 4; ++j) a[j] += (float)v[j];
        }
    }
    float inv = 1.0f / fmaxf((float)(end - beg), 1.0f);
    f16* o = A1b + (long)m * KP1 + 300 + off;
    #pragma unroll
    for (int h = 0; h < VW / 4; ++h) {
        f16x4 w = {(f16)(a[4*h] * inv), (f16)(a[4*h+1] * inv),
                   (f16)(a[4*h+2] * inv), (f16)(a[4*h+3] * inv)};
        *(f16x4*)(o + 4 * h) = w;  // 8B-aligned (300+off is even)
    }
}

// gather2 segment: out[m][c] = mean_e(t2[src][c]) + self[m][c], feats [c0, c0+64)
__global__ __launch_bounds__(256) void gather2_kernel(const int* __restrict__ row_ptr,
                                                      const int* __restrict__ csr,
                                                      const f16* __restrict__ t2,
                                                      const float* __restrict__ self,
                                                      float* __restrict__ out, int c0) {
    long idx = (long)blockIdx.x * 256 + threadIdx.x;  // m*8 + j
    if (idx >= (long)NN * 8) return;
    int m = (int)(idx / 8);
    int off = c0 + (int)(idx % 8) * 8;
    int beg = row_ptr[m], end = row_ptr[m + 1];
    float a[8] = {};
    for (int e = beg; e < end; ++e) {
        int s = csr[e];
        f16x8 v = *(const f16x8*)(t2 + (long)s * F2 + off);
        #pragma unroll
        for (int j = 0; j < 8; ++j) a[j] += (float)v[j];
    }
    float inv = 1.0f / fmaxf((float)(end - beg), 1.0f);
    const float* sp = self + (long)m * F2 + off;
    f32x4 s0 = *(const f32x4*)(sp);
    f32x4 s1 = *(const f32x4*)(sp + 4);
    f32x4 w0 = {a[0]*inv + s0[0], a[1]*inv + s0[1], a[2]*inv + s0[2], a[3]*inv + s0[3]};
    f32x4 w1 = {a[4]*inv + s1[0], a[5]*inv + s1[1], a[6]*inv + s1[2], a[7]*inv + s1[3]};
    float* op = out + (long)m * F2 + off;
    *(f32x4*)(op) = w0;
    *(f32x4*)(op + 4) = w1;
}

// ---------------- f16 MFMA GEMM ----------------
// C = A[M][K] @ Bt[N][K]^T, 128x128 tile, BK=64, 4 waves (2x2), 4x4 16x16x32 frags.
// MODE 1: h1 = relu(C + bias) (f16, row stride N)
// MODE 2: mixed layer-2 epilogue: n<F2 -> t2[m][n]=f16(C); n>=F2 -> self[m][n-F2]=C+bias[n-F2]
template<int MODE>
__global__ __launch_bounds__(256) void hgemm_kernel(
    const f16* __restrict__ A, const f16* __restrict__ Bt,
    const float* __restrict__ bias, float* __restrict__ out_f32,
    f16* __restrict__ out_f16, int M, int N, int K)
{
    __shared__ f16 As[128][72];  // 64 + 8 pad
    __shared__ f16 Bs[128][72];

    const int t = threadIdx.x;
    const int lane = t & 63, wave = t >> 6;
    const int wr = wave >> 1, wc = wave & 1;
    const int m0 = blockIdx.x * 128, n0 = blockIdx.y * 128;
    const int r = t >> 1, kh = (t & 1) * 32;

    f32x4 acc[4][4] = {};

    for (int k0 = 0; k0 < K; k0 += 64) {
        {
            const f16* ga = A + (long)(m0 + r) * K + k0 + kh;
            bool mok = (m0 + r) < M;
            f16x8 v0 = mok ? *(const f16x8*)(ga + 0)  : (f16x8){};
            f16x8 v1 = mok ? *(const f16x8*)(ga + 8)  : (f16x8){};
            f16x8 v2 = mok ? *(const f16x8*)(ga + 16) : (f16x8){};
            f16x8 v3 = mok ? *(const f16x8*)(ga + 24) : (f16x8){};
            *(f16x8*)&As[r][kh + 0]  = v0;
            *(f16x8*)&As[r][kh + 8]  = v1;
            *(f16x8*)&As[r][kh + 16] = v2;
            *(f16x8*)&As[r][kh + 24] = v3;
        }
        {
            const f16* gb = Bt + (long)(n0 + r) * K + k0 + kh;
            f16x8 v0 = *(const f16x8*)(gb + 0);
            f16x8 v1 = *(const f16x8*)(gb + 8);
            f16x8 v2 = *(const f16x8*)(gb + 16);
            f16x8 v3 = *(const f16x8*)(gb + 24);
            *(f16x8*)&Bs[r][kh + 0]  = v0;
            *(f16x8*)&Bs[r][kh + 8]  = v1;
            *(f16x8*)&Bs[r][kh + 16] = v2;
            *(f16x8*)&Bs[r][kh + 24] = v3;
        }
        __syncthreads();
        #pragma unroll
        for (int kk = 0; kk < 2; ++kk) {
            f16x8 af[4], bf[4];
            #pragma unroll
            for (int i = 0; i < 4; ++i)
                af[i] = *(const f16x8*)&As[wr * 64 + i * 16 + (lane & 15)][kk * 32 + (lane >> 4) * 8];
            #pragma unroll
            for (int j = 0; j < 4; ++j)
                bf[j] = *(const f16x8*)&Bs[wc * 64 + j * 16 + (lane & 15)][kk * 32 + (lane >> 4) * 8];
            #pragma unroll
            for (int i = 0; i < 4; ++i)
                #pragma unroll
                for (int j = 0; j < 4; ++j)
                    acc[i][j] = __builtin_amdgcn_mfma_f32_16x16x32_f16(af[i], bf[j], acc[i][j], 0, 0, 0);
        }
        __syncthreads();
    }

    // C/D layout: col = lane&15, row = (lane>>4)*4 + q
    const int cr = (lane >> 4) * 4, cc = lane & 15;
    #pragma unroll
    for (int i = 0; i < 4; ++i) {
        #pragma unroll
        for (int j = 0; j < 4; ++j) {
            int n = n0 + wc * 64 + j * 16 + cc;
            float b;
            if (MODE == 1) b = bias[n];
            else           b = (n >= F2) ? bias[n - F2] : 0.f;
            #pragma unroll
            for (int q = 0; q < 4; ++q) {
                int m = m0 + wr * 64 + i * 16 + cr + q;
                if (m >= M) continue;
                float v = acc[i][j][q];
                if (MODE == 1) {
                    out_f16[(long)m * N + n] = (f16)fmaxf(v + b, 0.f);
                } else {
                    if (n < F2) out_f16[(long)m * F2 + n] = (f16)v;
                    else        out_f32[(long)m * F2 + (n - F2)] = v + b;
                }
            }
        }
    }
}

extern "C" void kernel_launch(void* const* d_in, const int* in_sizes, int n_in,
                              void* d_out, int out_size, void* d_ws, size_t ws_size,
                              hipStream_t stream) {
    const float* x   = (const float*)d_in[0];
    const float* Ws1 = (const float*)d_in[1];
    const float* Wn1 = (const float*)d_in[2];
    const float* b1  = (const float*)d_in[3];
    const float* Ws2 = (const float*)d_in[4];
    const float* Wn2 = (const float*)d_in[5];
    const float* b2  = (const float*)d_in[6];
    const int* src   = (const int*)d_in[7];
    const int* dst   = (const int*)d_in[8];
    float* out = (float*)d_out;

    // workspace layout (bytes, 16B aligned):
    char* ws = (char*)d_ws;
    int* row_ptr = (int*)(ws);                      // 20001 i32   [0 .. 80,064)
    int* csr_src = (int*)(ws + 80064);              // 640000 i32  [80,064 .. 2,640,064)
    int* cursor  = (int*)(ws + 2640064);            // 20000 i32   [.. 2,720,064)
    f16* A1b     = (f16*)(ws + 2720064);            // 20000x640   [.. 28,320,064)
    f16* h1      = (f16*)(ws + 28320064);           // 20000x512   [.. 48,800,064)
    f16* t2      = (f16*)(ws + 48800064);           // 20000x256   [.. 59,040,064)
    float* selfp = (float*)(ws + 59040064);         // 20000x256 f32 [.. 79,520,064)
    f16* Wt1     = (f16*)(ws + 79520064);           // 512x640     [.. 80,175,424)
    f16* Wt2cat  = (f16*)(ws + 80175424);           // 512x512     [.. 80,699,712)

    // ---- prep: conversions + CSR build ----
    conv_x_kernel<<<(int)(((long)NN * 80) / 256), 256, 0, stream>>>(x, A1b);
    prep_w1_kernel<<<(F1 * KP1) / 256, 256, 0, stream>>>(Ws1, Wn1, Wt1);
    prep_w2cat_kernel<<<(2 * F2 * F1) / 256, 256, 0, stream>>>(Ws2, Wn2, Wt2cat);

    hipMemsetAsync(cursor, 0, NN * sizeof(int), stream);
    count_kernel<<<(NE + 255) / 256, 256, 0, stream>>>(dst, cursor);
    scan_kernel<<<1, 1024, 0, stream>>>(cursor, row_ptr, cursor);
    fill_kernel<<<(NE + 255) / 256, 256, 0, stream>>>(src, dst, cursor, csr_src);

    // ---- layer 1: segmented gather (4x64 + 1x44 feats), then concat-GEMM + relu ----
    for (int s = 0; s < 4; ++s)
        gather1_kernel<8, 8><<<(NN * 8 + 255) / 256, 256, 0, stream>>>(row_ptr, csr_src, A1b, s * 64);
    gather1_kernel<4, 11><<<(NN * 11 + 255) / 256, 256, 0, stream>>>(row_ptr, csr_src, A1b, 256);

    dim3 g1((NN + 127) / 128, F1 / 128);
    hgemm_kernel<1><<<g1, 256, 0, stream>>>(A1b, Wt1, b1, nullptr, h1, NN, F1, KP1);

    // ---- layer 2: fused [t2 | self] GEMM, then segmented gather+add ----
    dim3 g2((NN + 127) / 128, (2 * F2) / 128);
    hgemm_kernel<2><<<g2, 256, 0, stream>>>(h1, Wt2cat, b2, selfp, t2, NN, 2 * F2, F1);

    for (int s = 0; s < 4; ++s)
        gather2_kernel<<<(NN * 8 + 255) / 256, 256, 0, stream>>>(row_ptr, csr_src, t2, selfp, out, s * 64);
}

// Round 6
// 456.787 us; speedup vs baseline: 1.2370x; 1.2370x over previous
//
#include <hip/hip_runtime.h>

// GraphSAGE 2-layer forward, MI355X. Round 5:
//  - merged chunk-major gathers: ONE dispatch, segment = slowest block coord
//    (L2-resident 2.56MB window) with full thread count (TLP) — fixes round-4's
//    latency-bound per-segment dispatches.
//  - BM=64 x BN=128 GEMM tiles -> 1252 blocks (was 628), occupancy 20%->~60%.
// A1b[20000][640] f16 = [x(300) | 0(20) | agg(300) | 0(20)]
// h1 = relu(A1b @ Wt1^T + b1) (f16)
// [t2 | self] = h1 @ [Wn2^T | Ws2^T]; out = mean_agg(t2) + self

typedef _Float16 f16;
typedef _Float16 f16x4 __attribute__((ext_vector_type(4)));
typedef _Float16 f16x8 __attribute__((ext_vector_type(8)));
typedef float f32x4 __attribute__((ext_vector_type(4)));

constexpr int NN = 20000;   // nodes
constexpr int NE = 640000;  // edges
constexpr int F0 = 300;     // in feats
constexpr int F1 = 512;     // hidden
constexpr int F2 = 256;     // classes
constexpr int KP1 = 640;    // padded concat-K for layer 1
constexpr int XOFF = 320;   // agg region start inside A1b row

// ---------------- input conversion ----------------
// x f32 -> A1b cols 0..299 (f16); zero cols 300..319
__global__ void conv_x_kernel(const float* __restrict__ x, f16* __restrict__ A1b) {
    long idx = (long)blockIdx.x * 256 + threadIdx.x;  // m*80 + c
    if (idx >= (long)NN * 80) return;
    int m = (int)(idx / 80), c = (int)(idx % 80);
    if (c < 75) {
        float4 v = *(const float4*)(x + (long)m * F0 + 4 * c);
        f16x4 h = {(f16)v.x, (f16)v.y, (f16)v.z, (f16)v.w};
        *(f16x4*)(A1b + (long)m * KP1 + 4 * c) = h;
    } else {
        f16x4 z = {};
        *(f16x4*)(A1b + (long)m * KP1 + 300 + (c - 75) * 4) = z;
    }
}

// Wt1[n][k] (f16, [512][640]) : k<300 -> Ws1[k][n]; 300..319 -> 0;
//                               320..619 -> Wn1[k-320][n]; 620..639 -> 0
__global__ void prep_w1_kernel(const float* __restrict__ Ws1, const float* __restrict__ Wn1,
                               f16* __restrict__ Wt1) {
    int idx = blockIdx.x * 256 + threadIdx.x;
    if (idx >= F1 * KP1) return;
    int n = idx / KP1, k = idx % KP1;
    float v = 0.f;
    if (k < 300) v = Ws1[k * F1 + n];
    else if (k >= XOFF && k < XOFF + 300) v = Wn1[(k - XOFF) * F1 + n];
    Wt1[idx] = (f16)v;
}

// Wt2cat[n][k] ([512][512]) : n<256 -> Wn2[k][n] ; n>=256 -> Ws2[k][n-256]
__global__ void prep_w2cat_kernel(const float* __restrict__ Ws2, const float* __restrict__ Wn2,
                                  f16* __restrict__ Wt) {
    int idx = blockIdx.x * 256 + threadIdx.x;
    if (idx >= 2 * F2 * F1) return;
    int n = idx / F1, k = idx % F1;
    float v = (n < F2) ? Wn2[k * F2 + n] : Ws2[k * F2 + (n - F2)];
    Wt[idx] = (f16)v;
}

// ---------------- CSR build ----------------
__global__ void count_kernel(const int* __restrict__ dst, int* __restrict__ cnt) {
    int e = blockIdx.x * 256 + threadIdx.x;
    if (e < NE) atomicAdd(&cnt[dst[e]], 1);
}

__global__ __launch_bounds__(1024) void scan_kernel(const int* __restrict__ cnt,
                                                    int* __restrict__ row_ptr,
                                                    int* __restrict__ cursor) {
    constexpr int CH = (NN + 1023) / 1024;  // 20
    __shared__ int part[1024];
    const int t = threadIdx.x;
    int base = t * CH;
    int s = 0;
    #pragma unroll
    for (int i = 0; i < CH; ++i) {
        int idx = base + i;
        if (idx < NN) s += cnt[idx];
    }
    part[t] = s;
    __syncthreads();
    #pragma unroll
    for (int off = 1; off < 1024; off <<= 1) {
        int v = (t >= off) ? part[t - off] : 0;
        __syncthreads();
        part[t] += v;
        __syncthreads();
    }
    int run = (t == 0) ? 0 : part[t - 1];
    #pragma unroll
    for (int i = 0; i < CH; ++i) {
        int idx = base + i;
        if (idx < NN) {
            row_ptr[idx] = run;
            cursor[idx] = run;
            run += cnt[idx];
        }
    }
    if (t == 1023) row_ptr[NN] = part[1023];
}

__global__ void fill_kernel(const int* __restrict__ src, const int* __restrict__ dst,
                            int* __restrict__ cursor, int* __restrict__ csr_src) {
    int e = blockIdx.x * 256 + threadIdx.x;
    if (e >= NE) return;
    int pos = atomicAdd(&cursor[dst[e]], 1);
    csr_src[pos] = src[e];
}

// ---------------- merged chunk-major gathers ----------------
// NSEG segments x 625 blocks; seg = blockIdx.x/625 (slowest) so in-flight blocks
// share a 64-feat (128B/row) window -> 2.56MB table slice, L2-resident.
// 8 lanes per node: 128B contiguous per edge-visit.

// gather1: reads A1b cols [seg*64, seg*64+64), writes mean to cols XOFF + same
__global__ __launch_bounds__(256) void gather1_kernel(const int* __restrict__ row_ptr,
                                                      const int* __restrict__ csr,
                                                      f16* __restrict__ A1b) {
    int seg = blockIdx.x / 625;
    int g = (blockIdx.x % 625) * 256 + threadIdx.x;  // 0..159999
    int m = g >> 3;
    int off = seg * 64 + (g & 7) * 8;
    int beg = row_ptr[m], end = row_ptr[m + 1];
    float a[8] = {};
    for (int e = beg; e < end; ++e) {
        int s = csr[e];
        f16x8 v = *(const f16x8*)(A1b + (long)s * KP1 + off);
        #pragma unroll
        for (int j = 0; j < 8; ++j) a[j] += (float)v[j];
    }
    float inv = 1.0f / fmaxf((float)(end - beg), 1.0f);
    f16x8 w;
    #pragma unroll
    for (int j = 0; j < 8; ++j) w[j] = (f16)(a[j] * inv);
    *(f16x8*)(A1b + (long)m * KP1 + XOFF + off) = w;
}

// gather2: out[m][c] = mean_e(t2[src][c]) + self[m][c]
__global__ __launch_bounds__(256) void gather2_kernel(const int* __restrict__ row_ptr,
                                                      const int* __restrict__ csr,
                                                      const f16* __restrict__ t2,
                                                      const float* __restrict__ self,
                                                      float* __restrict__ out) {
    int seg = blockIdx.x / 625;
    int g = (blockIdx.x % 625) * 256 + threadIdx.x;
    int m = g >> 3;
    int off = seg * 64 + (g & 7) * 8;
    int beg = row_ptr[m], end = row_ptr[m + 1];
    float a[8] = {};
    for (int e = beg; e < end; ++e) {
        int s = csr[e];
        f16x8 v = *(const f16x8*)(t2 + (long)s * F2 + off);
        #pragma unroll
        for (int j = 0; j < 8; ++j) a[j] += (float)v[j];
    }
    float inv = 1.0f / fmaxf((float)(end - beg), 1.0f);
    const float* sp = self + (long)m * F2 + off;
    f32x4 s0 = *(const f32x4*)(sp);
    f32x4 s1 = *(const f32x4*)(sp + 4);
    f32x4 w0 = {a[0]*inv + s0[0], a[1]*inv + s0[1], a[2]*inv + s0[2], a[3]*inv + s0[3]};
    f32x4 w1 = {a[4]*inv + s1[0], a[5]*inv + s1[1], a[6]*inv + s1[2], a[7]*inv + s1[3]};
    float* op = out + (long)m * F2 + off;
    *(f32x4*)(op) = w0;
    *(f32x4*)(op + 4) = w1;
}

// ---------------- f16 MFMA GEMM ----------------
// C = A[M][K] @ Bt[N][K]^T. BM=64, BN=128, BK=64; 4 waves (2x2), wave tile 32x64
// (2x4 16x16x32 frags). Grid (ceil(M/64), N/128).
// MODE 1: h1 = relu(C + bias) (f16)
// MODE 2: n<F2 -> t2[m][n] = f16(C); n>=F2 -> self[m][n-F2] = C + bias[n-F2] (f32)
template<int MODE>
__global__ __launch_bounds__(256) void hgemm_kernel(
    const f16* __restrict__ A, const f16* __restrict__ Bt,
    const float* __restrict__ bias, float* __restrict__ out_f32,
    f16* __restrict__ out_f16, int M, int N, int K)
{
    __shared__ f16 As[64][72];
    __shared__ f16 Bs[128][72];

    const int t = threadIdx.x;
    const int lane = t & 63, wave = t >> 6;
    const int wr = wave >> 1, wc = wave & 1;
    const int m0 = blockIdx.x * 64, n0 = blockIdx.y * 128;
    const int ar = t >> 2, ac = (t & 3) * 16;  // A staging: row, col (2x f16x8)
    const int br = t >> 1, bc = (t & 1) * 32;  // B staging: row, col (4x f16x8)

    f32x4 acc[2][4] = {};

    for (int k0 = 0; k0 < K; k0 += 64) {
        {
            const f16* ga = A + (long)(m0 + ar) * K + k0 + ac;
            bool mok = (m0 + ar) < M;
            f16x8 v0 = mok ? *(const f16x8*)(ga + 0) : (f16x8){};
            f16x8 v1 = mok ? *(const f16x8*)(ga + 8) : (f16x8){};
            *(f16x8*)&As[ar][ac + 0] = v0;
            *(f16x8*)&As[ar][ac + 8] = v1;
        }
        {
            const f16* gb = Bt + (long)(n0 + br) * K + k0 + bc;
            f16x8 v0 = *(const f16x8*)(gb + 0);
            f16x8 v1 = *(const f16x8*)(gb + 8);
            f16x8 v2 = *(const f16x8*)(gb + 16);
            f16x8 v3 = *(const f16x8*)(gb + 24);
            *(f16x8*)&Bs[br][bc + 0]  = v0;
            *(f16x8*)&Bs[br][bc + 8]  = v1;
            *(f16x8*)&Bs[br][bc + 16] = v2;
            *(f16x8*)&Bs[br][bc + 24] = v3;
        }
        __syncthreads();
        #pragma unroll
        for (int kk = 0; kk < 2; ++kk) {
            f16x8 af[2], bf[4];
            #pragma unroll
            for (int i = 0; i < 2; ++i)
                af[i] = *(const f16x8*)&As[wr * 32 + i * 16 + (lane & 15)][kk * 32 + (lane >> 4) * 8];
            #pragma unroll
            for (int j = 0; j < 4; ++j)
                bf[j] = *(const f16x8*)&Bs[wc * 64 + j * 16 + (lane & 15)][kk * 32 + (lane >> 4) * 8];
            #pragma unroll
            for (int i = 0; i < 2; ++i)
                #pragma unroll
                for (int j = 0; j < 4; ++j)
                    acc[i][j] = __builtin_amdgcn_mfma_f32_16x16x32_f16(af[i], bf[j], acc[i][j], 0, 0, 0);
        }
        __syncthreads();
    }

    // C/D layout: col = lane&15, row = (lane>>4)*4 + q  [m89-verified]
    const int cr = (lane >> 4) * 4, cc = lane & 15;
    #pragma unroll
    for (int i = 0; i < 2; ++i) {
        #pragma unroll
        for (int j = 0; j < 4; ++j) {
            int n = n0 + wc * 64 + j * 16 + cc;
            float b;
            if (MODE == 1) b = bias[n];
            else           b = (n >= F2) ? bias[n - F2] : 0.f;
            #pragma unroll
            for (int q = 0; q < 4; ++q) {
                int m = m0 + wr * 32 + i * 16 + cr + q;
                if (m >= M) continue;
                float v = acc[i][j][q];
                if (MODE == 1) {
                    out_f16[(long)m * N + n] = (f16)fmaxf(v + b, 0.f);
                } else {
                    if (n < F2) out_f16[(long)m * F2 + n] = (f16)v;
                    else        out_f32[(long)m * F2 + (n - F2)] = v + b;
                }
            }
        }
    }
}

extern "C" void kernel_launch(void* const* d_in, const int* in_sizes, int n_in,
                              void* d_out, int out_size, void* d_ws, size_t ws_size,
                              hipStream_t stream) {
    const float* x   = (const float*)d_in[0];
    const float* Ws1 = (const float*)d_in[1];
    const float* Wn1 = (const float*)d_in[2];
    const float* b1  = (const float*)d_in[3];
    const float* Ws2 = (const float*)d_in[4];
    const float* Wn2 = (const float*)d_in[5];
    const float* b2  = (const float*)d_in[6];
    const int* src   = (const int*)d_in[7];
    const int* dst   = (const int*)d_in[8];
    float* out = (float*)d_out;

    // workspace layout (bytes, 16B aligned):
    char* ws = (char*)d_ws;
    int* row_ptr = (int*)(ws);                      // 20001 i32   [0 .. 80,064)
    int* csr_src = (int*)(ws + 80064);              // 640000 i32  [.. 2,640,064)
    int* cursor  = (int*)(ws + 2640064);            // 20000 i32   [.. 2,720,064)
    f16* A1b     = (f16*)(ws + 2720064);            // 20000x640   [.. 28,320,064)
    f16* h1      = (f16*)(ws + 28320064);           // 20000x512   [.. 48,800,064)
    f16* t2      = (f16*)(ws + 48800064);           // 20000x256   [.. 59,040,064)
    float* selfp = (float*)(ws + 59040064);         // 20000x256 f32 [.. 79,520,064)
    f16* Wt1     = (f16*)(ws + 79520064);           // 512x640     [.. 80,175,424)
    f16* Wt2cat  = (f16*)(ws + 80175424);           // 512x512     [.. 80,699,712)

    // ---- prep: conversions + CSR build ----
    conv_x_kernel<<<(int)(((long)NN * 80) / 256), 256, 0, stream>>>(x, A1b);
    prep_w1_kernel<<<(F1 * KP1) / 256, 256, 0, stream>>>(Ws1, Wn1, Wt1);
    prep_w2cat_kernel<<<(2 * F2 * F1) / 256, 256, 0, stream>>>(Ws2, Wn2, Wt2cat);

    hipMemsetAsync(cursor, 0, NN * sizeof(int), stream);
    count_kernel<<<(NE + 255) / 256, 256, 0, stream>>>(dst, cursor);
    scan_kernel<<<1, 1024, 0, stream>>>(cursor, row_ptr, cursor);
    fill_kernel<<<(NE + 255) / 256, 256, 0, stream>>>(src, dst, cursor, csr_src);

    // ---- layer 1: merged gather (5 segments in one dispatch), concat-GEMM + relu ----
    gather1_kernel<<<5 * 625, 256, 0, stream>>>(row_ptr, csr_src, A1b);
    dim3 g1((NN + 63) / 64, F1 / 128);
    hgemm_kernel<1><<<g1, 256, 0, stream>>>(A1b, Wt1, b1, nullptr, h1, NN, F1, KP1);

    // ---- layer 2: fused [t2 | self] GEMM, then merged gather+add ----
    dim3 g2((NN + 63) / 64, (2 * F2) / 128);
    hgemm_kernel<2><<<g2, 256, 0, stream>>>(h1, Wt2cat, b2, selfp, t2, NN, 2 * F2, F1);
    gather2_kernel<<<4 * 625, 256, 0, stream>>>(row_ptr, csr_src, t2, selfp, out);
}

// Round 8
// 417.097 us; speedup vs baseline: 1.3547x; 1.0952x over previous
//
#include <hip/hip_runtime.h>

// GraphSAGE 2-layer forward, MI355X. Round 6 (resubmit after broker timeout):
//  - XCD-contiguous bijective block swizzle on the merged chunk-major gathers:
//    each XCD sweeps the segment-major work sequence contiguously, so its L2
//    holds ~1 feature-window (2.56MB) at a time instead of thrashing 2-3.
//  - GEMMs unchanged from Round 5 (BM=64 x BN=128).
// A1b[20000][640] f16 = [x(300) | 0(20) | agg(300) | 0(20)]
// h1 = relu(A1b @ Wt1^T + b1) (f16)
// [t2 | self] = h1 @ [Wn2^T | Ws2^T]; out = mean_agg(t2) + self

typedef _Float16 f16;
typedef _Float16 f16x4 __attribute__((ext_vector_type(4)));
typedef _Float16 f16x8 __attribute__((ext_vector_type(8)));
typedef float f32x4 __attribute__((ext_vector_type(4)));

constexpr int NN = 20000;   // nodes
constexpr int NE = 640000;  // edges
constexpr int F0 = 300;     // in feats
constexpr int F1 = 512;     // hidden
constexpr int F2 = 256;     // classes
constexpr int KP1 = 640;    // padded concat-K for layer 1
constexpr int XOFF = 320;   // agg region start inside A1b row

// bijective XCD-contiguous swizzle (m204): XCD x owns a contiguous range of the
// logical work sequence; hardware round-robins blockIdx across XCDs (%8).
__device__ __forceinline__ int xcd_swz(int b, int nb) {
    int xcd = b & 7, loc = b >> 3;
    int q = nb >> 3, r = nb & 7;
    return (xcd < r ? xcd * (q + 1) : r * (q + 1) + (xcd - r) * q) + loc;
}

// ---------------- input conversion ----------------
__global__ void conv_x_kernel(const float* __restrict__ x, f16* __restrict__ A1b) {
    long idx = (long)blockIdx.x * 256 + threadIdx.x;  // m*80 + c
    if (idx >= (long)NN * 80) return;
    int m = (int)(idx / 80), c = (int)(idx % 80);
    if (c < 75) {
        float4 v = *(const float4*)(x + (long)m * F0 + 4 * c);
        f16x4 h = {(f16)v.x, (f16)v.y, (f16)v.z, (f16)v.w};
        *(f16x4*)(A1b + (long)m * KP1 + 4 * c) = h;
    } else {
        f16x4 z = {};
        *(f16x4*)(A1b + (long)m * KP1 + 300 + (c - 75) * 4) = z;
    }
}

// Wt1[n][k] (f16, [512][640]) : k<300 -> Ws1[k][n]; 300..319 -> 0;
//                               320..619 -> Wn1[k-320][n]; 620..639 -> 0
__global__ void prep_w1_kernel(const float* __restrict__ Ws1, const float* __restrict__ Wn1,
                               f16* __restrict__ Wt1) {
    int idx = blockIdx.x * 256 + threadIdx.x;
    if (idx >= F1 * KP1) return;
    int n = idx / KP1, k = idx % KP1;
    float v = 0.f;
    if (k < 300) v = Ws1[k * F1 + n];
    else if (k >= XOFF && k < XOFF + 300) v = Wn1[(k - XOFF) * F1 + n];
    Wt1[idx] = (f16)v;
}

// Wt2cat[n][k] ([512][512]) : n<256 -> Wn2[k][n] ; n>=256 -> Ws2[k][n-256]
__global__ void prep_w2cat_kernel(const float* __restrict__ Ws2, const float* __restrict__ Wn2,
                                  f16* __restrict__ Wt) {
    int idx = blockIdx.x * 256 + threadIdx.x;
    if (idx >= 2 * F2 * F1) return;
    int n = idx / F1, k = idx % F1;
    float v = (n < F2) ? Wn2[k * F2 + n] : Ws2[k * F2 + (n - F2)];
    Wt[idx] = (f16)v;
}

// ---------------- CSR build ----------------
__global__ void count_kernel(const int* __restrict__ dst, int* __restrict__ cnt) {
    int e = blockIdx.x * 256 + threadIdx.x;
    if (e < NE) atomicAdd(&cnt[dst[e]], 1);
}

__global__ __launch_bounds__(1024) void scan_kernel(const int* __restrict__ cnt,
                                                    int* __restrict__ row_ptr,
                                                    int* __restrict__ cursor) {
    constexpr int CH = (NN + 1023) / 1024;  // 20
    __shared__ int part[1024];
    const int t = threadIdx.x;
    int base = t * CH;
    int s = 0;
    #pragma unroll
    for (int i = 0; i < CH; ++i) {
        int idx = base + i;
        if (idx < NN) s += cnt[idx];
    }
    part[t] = s;
    __syncthreads();
    #pragma unroll
    for (int off = 1; off < 1024; off <<= 1) {
        int v = (t >= off) ? part[t - off] : 0;
        __syncthreads();
        part[t] += v;
        __syncthreads();
    }
    int run = (t == 0) ? 0 : part[t - 1];
    #pragma unroll
    for (int i = 0; i < CH; ++i) {
        int idx = base + i;
        if (idx < NN) {
            row_ptr[idx] = run;
            cursor[idx] = run;
            run += cnt[idx];
        }
    }
    if (t == 1023) row_ptr[NN] = part[1023];
}

__global__ void fill_kernel(const int* __restrict__ src, const int* __restrict__ dst,
                            int* __restrict__ cursor, int* __restrict__ csr_src) {
    int e = blockIdx.x * 256 + threadIdx.x;
    if (e >= NE) return;
    int pos = atomicAdd(&cursor[dst[e]], 1);
    csr_src[pos] = src[e];
}

// ---------------- merged chunk-major gathers (XCD-swizzled) ----------------
// Work item g = (seg, node, lane8): seg-major. xcd_swz gives each XCD a
// contiguous g-range -> its L2 holds ~one 64-feat window (20000x128B = 2.56MB).

// gather1: reads A1b cols [seg*64, seg*64+64), writes mean to cols XOFF + same
__global__ __launch_bounds__(256) void gather1_kernel(const int* __restrict__ row_ptr,
                                                      const int* __restrict__ csr,
                                                      f16* __restrict__ A1b) {
    int wid = xcd_swz(blockIdx.x, 5 * 625);
    int seg = wid / 625;
    int g = (wid % 625) * 256 + threadIdx.x;  // 0..159999
    int m = g >> 3;
    int off = seg * 64 + (g & 7) * 8;
    int beg = row_ptr[m], end = row_ptr[m + 1];
    float a[8] = {};
    for (int e = beg; e < end; ++e) {
        int s = csr[e];
        f16x8 v = *(const f16x8*)(A1b + (long)s * KP1 + off);
        #pragma unroll
        for (int j = 0; j < 8; ++j) a[j] += (float)v[j];
    }
    float inv = 1.0f / fmaxf((float)(end - beg), 1.0f);
    f16x8 w;
    #pragma unroll
    for (int j = 0; j < 8; ++j) w[j] = (f16)(a[j] * inv);
    *(f16x8*)(A1b + (long)m * KP1 + XOFF + off) = w;
}

// gather2: out[m][c] = mean_e(t2[src][c]) + self[m][c]
__global__ __launch_bounds__(256) void gather2_kernel(const int* __restrict__ row_ptr,
                                                      const int* __restrict__ csr,
                                                      const f16* __restrict__ t2,
                                                      const float* __restrict__ self,
                                                      float* __restrict__ out) {
    int wid = xcd_swz(blockIdx.x, 4 * 625);
    int seg = wid / 625;
    int g = (wid % 625) * 256 + threadIdx.x;
    int m = g >> 3;
    int off = seg * 64 + (g & 7) * 8;
    int beg = row_ptr[m], end = row_ptr[m + 1];
    float a[8] = {};
    for (int e = beg; e < end; ++e) {
        int s = csr[e];
        f16x8 v = *(const f16x8*)(t2 + (long)s * F2 + off);
        #pragma unroll
        for (int j = 0; j < 8; ++j) a[j] += (float)v[j];
    }
    float inv = 1.0f / fmaxf((float)(end - beg), 1.0f);
    const float* sp = self + (long)m * F2 + off;
    f32x4 s0 = *(const f32x4*)(sp);
    f32x4 s1 = *(const f32x4*)(sp + 4);
    f32x4 w0 = {a[0]*inv + s0[0], a[1]*inv + s0[1], a[2]*inv + s0[2], a[3]*inv + s0[3]};
    f32x4 w1 = {a[4]*inv + s1[0], a[5]*inv + s1[1], a[6]*inv + s1[2], a[7]*inv + s1[3]};
    float* op = out + (long)m * F2 + off;
    *(f32x4*)(op) = w0;
    *(f32x4*)(op + 4) = w1;
}

// ---------------- f16 MFMA GEMM ----------------
// C = A[M][K] @ Bt[N][K]^T. BM=64, BN=128, BK=64; 4 waves (2x2), wave tile 32x64.
// MODE 1: h1 = relu(C + bias) (f16)
// MODE 2: n<F2 -> t2[m][n] = f16(C); n>=F2 -> self[m][n-F2] = C + bias[n-F2] (f32)
template<int MODE>
__global__ __launch_bounds__(256) void hgemm_kernel(
    const f16* __restrict__ A, const f16* __restrict__ Bt,
    const float* __restrict__ bias, float* __restrict__ out_f32,
    f16* __restrict__ out_f16, int M, int N, int K)
{
    __shared__ f16 As[64][72];
    __shared__ f16 Bs[128][72];

    const int t = threadIdx.x;
    const int lane = t & 63, wave = t >> 6;
    const int wr = wave >> 1, wc = wave & 1;
    const int m0 = blockIdx.x * 64, n0 = blockIdx.y * 128;
    const int ar = t >> 2, ac = (t & 3) * 16;
    const int br = t >> 1, bc = (t & 1) * 32;

    f32x4 acc[2][4] = {};

    for (int k0 = 0; k0 < K; k0 += 64) {
        {
            const f16* ga = A + (long)(m0 + ar) * K + k0 + ac;
            bool mok = (m0 + ar) < M;
            f16x8 v0 = mok ? *(const f16x8*)(ga + 0) : (f16x8){};
            f16x8 v1 = mok ? *(const f16x8*)(ga + 8) : (f16x8){};
            *(f16x8*)&As[ar][ac + 0] = v0;
            *(f16x8*)&As[ar][ac + 8] = v1;
        }
        {
            const f16* gb = Bt + (long)(n0 + br) * K + k0 + bc;
            f16x8 v0 = *(const f16x8*)(gb + 0);
            f16x8 v1 = *(const f16x8*)(gb + 8);
            f16x8 v2 = *(const f16x8*)(gb + 16);
            f16x8 v3 = *(const f16x8*)(gb + 24);
            *(f16x8*)&Bs[br][bc + 0]  = v0;
            *(f16x8*)&Bs[br][bc + 8]  = v1;
            *(f16x8*)&Bs[br][bc + 16] = v2;
            *(f16x8*)&Bs[br][bc + 24] = v3;
        }
        __syncthreads();
        #pragma unroll
        for (int kk = 0; kk < 2; ++kk) {
            f16x8 af[2], bf[4];
            #pragma unroll
            for (int i = 0; i < 2; ++i)
                af[i] = *(const f16x8*)&As[wr * 32 + i * 16 + (lane & 15)][kk * 32 + (lane >> 4) * 8];
            #pragma unroll
            for (int j = 0; j < 4; ++j)
                bf[j] = *(const f16x8*)&Bs[wc * 64 + j * 16 + (lane & 15)][kk * 32 + (lane >> 4) * 8];
            #pragma unroll
            for (int i = 0; i < 2; ++i)
                #pragma unroll
                for (int j = 0; j < 4; ++j)
                    acc[i][j] = __builtin_amdgcn_mfma_f32_16x16x32_f16(af[i], bf[j], acc[i][j], 0, 0, 0);
        }
        __syncthreads();
    }

    // C/D layout: col = lane&15, row = (lane>>4)*4 + q  [m89-verified]
    const int cr = (lane >> 4) * 4, cc = lane & 15;
    #pragma unroll
    for (int i = 0; i < 2; ++i) {
        #pragma unroll
        for (int j = 0; j < 4; ++j) {
            int n = n0 + wc * 64 + j * 16 + cc;
            float b;
            if (MODE == 1) b = bias[n];
            else           b = (n >= F2) ? bias[n - F2] : 0.f;
            #pragma unroll
            for (int q = 0; q < 4; ++q) {
                int m = m0 + wr * 32 + i * 16 + cr + q;
                if (m >= M) continue;
                float v = acc[i][j][q];
                if (MODE == 1) {
                    out_f16[(long)m * N + n] = (f16)fmaxf(v + b, 0.f);
                } else {
                    if (n < F2) out_f16[(long)m * F2 + n] = (f16)v;
                    else        out_f32[(long)m * F2 + (n - F2)] = v + b;
                }
            }
        }
    }
}

extern "C" void kernel_launch(void* const* d_in, const int* in_sizes, int n_in,
                              void* d_out, int out_size, void* d_ws, size_t ws_size,
                              hipStream_t stream) {
    const float* x   = (const float*)d_in[0];
    const float* Ws1 = (const float*)d_in[1];
    const float* Wn1 = (const float*)d_in[2];
    const float* b1  = (const float*)d_in[3];
    const float* Ws2 = (const float*)d_in[4];
    const float* Wn2 = (const float*)d_in[5];
    const float* b2  = (const float*)d_in[6];
    const int* src   = (const int*)d_in[7];
    const int* dst   = (const int*)d_in[8];
    float* out = (float*)d_out;

    // workspace layout (bytes, 16B aligned):
    char* ws = (char*)d_ws;
    int* row_ptr = (int*)(ws);                      // 20001 i32   [0 .. 80,064)
    int* csr_src = (int*)(ws + 80064);              // 640000 i32  [.. 2,640,064)
    int* cursor  = (int*)(ws + 2640064);            // 20000 i32   [.. 2,720,064)
    f16* A1b     = (f16*)(ws + 2720064);            // 20000x640   [.. 28,320,064)
    f16* h1      = (f16*)(ws + 28320064);           // 20000x512   [.. 48,800,064)
    f16* t2      = (f16*)(ws + 48800064);           // 20000x256   [.. 59,040,064)
    float* selfp = (float*)(ws + 59040064);         // 20000x256 f32 [.. 79,520,064)
    f16* Wt1     = (f16*)(ws + 79520064);           // 512x640     [.. 80,175,424)
    f16* Wt2cat  = (f16*)(ws + 80175424);           // 512x512     [.. 80,699,712)

    // ---- prep: conversions + CSR build ----
    conv_x_kernel<<<(int)(((long)NN * 80) / 256), 256, 0, stream>>>(x, A1b);
    prep_w1_kernel<<<(F1 * KP1) / 256, 256, 0, stream>>>(Ws1, Wn1, Wt1);
    prep_w2cat_kernel<<<(2 * F2 * F1) / 256, 256, 0, stream>>>(Ws2, Wn2, Wt2cat);

    hipMemsetAsync(cursor, 0, NN * sizeof(int), stream);
    count_kernel<<<(NE + 255) / 256, 256, 0, stream>>>(dst, cursor);
    scan_kernel<<<1, 1024, 0, stream>>>(cursor, row_ptr, cursor);
    fill_kernel<<<(NE + 255) / 256, 256, 0, stream>>>(src, dst, cursor, csr_src);

    // ---- layer 1: merged gather (XCD-swizzled), concat-GEMM + relu ----
    gather1_kernel<<<5 * 625, 256, 0, stream>>>(row_ptr, csr_src, A1b);
    dim3 g1((NN + 63) / 64, F1 / 128);
    hgemm_kernel<1><<<g1, 256, 0, stream>>>(A1b, Wt1, b1, nullptr, h1, NN, F1, KP1);

    // ---- layer 2: fused [t2 | self] GEMM, then merged gather+add ----
    dim3 g2((NN + 63) / 64, (2 * F2) / 128);
    hgemm_kernel<2><<<g2, 256, 0, stream>>>(h1, Wt2cat, b2, selfp, t2, NN, 2 * F2, F1);
    gather2_kernel<<<4 * 625, 256, 0, stream>>>(row_ptr, csr_src, t2, selfp, out);
}